// Round 12
// baseline (206.200 us; speedup 1.0000x reference)
//
#include <hip/hip_runtime.h>
#include <hip/hip_bf16.h>

#define F_IN 256
#define HDIM 128
#define CDIM 16

typedef unsigned short u16;
typedef unsigned int u32;

typedef __attribute__((ext_vector_type(8))) short bf16x8;
typedef __attribute__((ext_vector_type(4))) float f32x4;

__device__ __forceinline__ float bf2f(u32 v) {
    u32 u = v << 16;
    float f;
    __builtin_memcpy(&f, &u, 4);
    return f;
}
__device__ __forceinline__ float asf(u32 u) {
    float f;
    __builtin_memcpy(&f, &u, 4);
    return f;
}
__device__ __forceinline__ u16 f2bf(float f) {
    u32 u;
    __builtin_memcpy(&u, &f, 4);
    u32 r = (u + 0x7FFFu + ((u >> 16) & 1u)) >> 16;
    return (u16)r;
}
// v_cvt_pk_bf16_f32: D[15:0]=bf16(lo), D[31:16]=bf16(hi), RNE
__device__ __forceinline__ u32 cvtpk(float lo, float hi) {
    u32 r;
    asm("v_cvt_pk_bf16_f32 %0, %1, %2" : "=v"(r) : "v"(lo), "v"(hi));
    return r;
}

// ---------------- K1: dinv[r] = rsqrt(sum_e ew[e]) ----------------
__global__ __launch_bounds__(256) void k_dinv(const float* __restrict__ ew,
                                              const int* __restrict__ rowptr,
                                              float* __restrict__ dinv, int n) {
    int sg = threadIdx.x >> 4;
    int sl = threadIdx.x & 15;
    int r = blockIdx.x * 16 + sg;
    if (r >= n) return;
    int s = rowptr[r], e = rowptr[r + 1];
    float acc = 0.f;
    for (int i = s + sl; i < e; i += 16) acc += ew[i];
    acc += __shfl_xor(acc, 1);
    acc += __shfl_xor(acc, 2);
    acc += __shfl_xor(acc, 4);
    acc += __shfl_xor(acc, 8);
    if (sl == 0) dinv[r] = (acc > 0.f) ? rsqrtf(acc) : 0.f;
}

// ---------------- K2: w[e] = dinv[row]*ew[e]*dinv[col[e]] ----------------
__global__ __launch_bounds__(256) void k_w(const float* __restrict__ ew,
                                           const int* __restrict__ rowptr,
                                           const int* __restrict__ col,
                                           const float* __restrict__ dinv,
                                           float* __restrict__ wn, int n) {
    int sg = threadIdx.x >> 4;
    int sl = threadIdx.x & 15;
    int r = blockIdx.x * 16 + sg;
    if (r >= n) return;
    float dr = dinv[r];
    int s = rowptr[r], e = rowptr[r + 1];
    for (int i = s + sl; i < e; i += 16)
        wn[i] = dr * ew[i] * dinv[col[i]];
}

// ---------------- K-prep: W1T[f][k] = bf16(W1[k][f])  (128x256 bf16) ----------------
__global__ void k_prepw1(const float* __restrict__ W1, u16* __restrict__ W1T) {
    int idx = blockIdx.x * blockDim.x + threadIdx.x;   // 0..32767
    if (idx >= HDIM * F_IN) return;
    int f = idx >> 8;         // 0..127
    int k = idx & 255;        // 0..255
    W1T[idx] = f2bf(W1[(size_t)k * HDIM + f]);
}

// ---------------- K3: T1 = x @ W1 via bf16 MFMA, W1T in LDS ----------
// Block = 8 waves x 32 rows = 256 rows. W1T (64 KB) in LDS, XOR-swizzled.
// 2 blocks/CU -> 16 waves/CU. x global->reg, 2-stage prefetch.
// D: col = lane&15, row = (lane>>4)*4 + reg   [m89-verified]
__global__ __launch_bounds__(512, 4) void k_gemm1(const float* __restrict__ x,
                                                  const u16* __restrict__ W1T,
                                                  u16* __restrict__ T1, int n) {
    __shared__ u16 Bs[HDIM * F_IN];   // 64 KB

    int tid = threadIdx.x;
#pragma unroll
    for (int it = 0; it < 8; it++) {
        int o16 = it * 512 + tid;            // 16B-granule index 0..4095
        u32 o = (u32)o16 * 16;
        u32 swz = o ^ (((o >> 9) & 7u) << 4);
        uint4 v = ((const uint4*)W1T)[o16];
        *(uint4*)((char*)Bs + swz) = v;
    }
    __syncthreads();

    int wave = tid >> 6;
    int lane = tid & 63;
    int lr = lane & 15;
    int kg = lane >> 4;
    int r0 = blockIdx.x * 256 + wave * 32;
    if (r0 >= n) return;

    f32x4 acc[2][8];
#pragma unroll
    for (int rg = 0; rg < 2; rg++)
#pragma unroll
        for (int ct = 0; ct < 8; ct++) acc[rg][ct] = (f32x4){0.f, 0.f, 0.f, 0.f};

    const float* arow[2];
#pragma unroll
    for (int rg = 0; rg < 2; rg++) {
        int row = r0 + rg * 16 + lr;
        arow[rg] = x + (size_t)(row < n ? row : (n - 1)) * F_IN + kg * 8;
    }

    float4 laA[2], haA[2], laB[2], haB[2];

#define LOADA(L_, H_, kkv_) do { \
        _Pragma("unroll") \
        for (int rg = 0; rg < 2; rg++) { \
            const float4* ap = (const float4*)(arow[rg] + (kkv_) * 32); \
            L_[rg] = ap[0]; H_[rg] = ap[1]; \
        } } while (0)

#define COMPUTE(L_, H_, kkv_) do { \
        bf16x8 afrag[2]; \
        _Pragma("unroll") \
        for (int rg = 0; rg < 2; rg++) { \
            u32 qa[4]; \
            qa[0] = cvtpk(L_[rg].x, L_[rg].y); \
            qa[1] = cvtpk(L_[rg].z, L_[rg].w); \
            qa[2] = cvtpk(H_[rg].x, H_[rg].y); \
            qa[3] = cvtpk(H_[rg].z, H_[rg].w); \
            __builtin_memcpy(&afrag[rg], qa, 16); \
        } \
        _Pragma("unroll") \
        for (int ct = 0; ct < 8; ct++) { \
            u32 a = (u32)(ct * 16 + lr) * (F_IN * 2) + (u32)kg * 16 + (u32)(kkv_) * 64; \
            u32 aswz = a ^ (((a >> 9) & 7u) << 4); \
            bf16x8 bfrag = *(const bf16x8*)((const char*)Bs + aswz); \
            _Pragma("unroll") \
            for (int rg = 0; rg < 2; rg++) \
                acc[rg][ct] = __builtin_amdgcn_mfma_f32_16x16x32_bf16(afrag[rg], bfrag, acc[rg][ct], 0, 0, 0); \
        } } while (0)

    LOADA(laA, haA, 0);
#pragma unroll
    for (int kk = 0; kk < 8; kk += 2) {
        LOADA(laB, haB, kk + 1);
        COMPUTE(laA, haA, kk);
        if (kk + 2 < 8) LOADA(laA, haA, kk + 2);
        COMPUTE(laB, haB, kk + 1);
    }
#undef LOADA
#undef COMPUTE

    // store: T1[r0 + rg*16 + kg*4 + i][ct*16 + lr]
#pragma unroll
    for (int rg = 0; rg < 2; rg++) {
        int rbase = r0 + rg * 16 + kg * 4;
#pragma unroll
        for (int ct = 0; ct < 8; ct++) {
#pragma unroll
            for (int i = 0; i < 4; i += 2) {
                u32 q = cvtpk(acc[rg][ct][i], acc[rg][ct][i + 1]);
                int row0 = rbase + i;
                int row1 = rbase + i + 1;
                if (row0 < n) T1[(size_t)row0 * HDIM + ct * 16 + lr] = (u16)(q & 0xFFFFu);
                if (row1 < n) T1[(size_t)row1 * HDIM + ct * 16 + lr] = (u16)(q >> 16);
            }
        }
    }
}

// ---------------- K4: U = relu(SpMM(T1) + b1) @ W2   (gemm2 FUSED) ----------
// 4 waves/block, 1 row/wave. Wave = 4x 16-lane subgroups, each owns one edge.
// nwin FULL windows (unguarded) + ONE guarded clamped tail window.
// After the butterfly reduce every lane holds the full 8-feature sum for
// features fl*8..fl*8+7 -> fuse: v = relu(a+b1) in f32, p4 = v @ W2[8x4 tile]
// (8 float4 loads from L1-hot W2), reduce p4 over fl, lanes fl==0 write U.
// H is never materialized (removes one bf16 rounding + 50 MB traffic).
__global__ __launch_bounds__(256) void k_spmm1(const u16* __restrict__ T1,
                                               const float* __restrict__ wn,
                                               const int* __restrict__ rowptr,
                                               const int* __restrict__ col,
                                               const float* __restrict__ b1,
                                               const float* __restrict__ W2,
                                               float* __restrict__ U, int n) {
    int wave = threadIdx.x >> 6;
    int lane = threadIdx.x & 63;
    int r = blockIdx.x * 4 + wave;
    if (r >= n) return;
    int es = lane >> 4;          // subgroup 0..3 (edge slot)
    int fl = lane & 15;          // feature group: features fl*8 .. fl*8+7

    int s = rowptr[r], e = rowptr[r + 1];
    int deg = e - s;
    int nwin = deg >> 4;
    float a[8];
#pragma unroll
    for (int j = 0; j < 8; j++) a[j] = 0.f;

#define ACCUM(w_, p_) do { \
        a[0] += (w_) * asf((p_).x << 16); a[1] += (w_) * asf((p_).x & 0xFFFF0000u); \
        a[2] += (w_) * asf((p_).y << 16); a[3] += (w_) * asf((p_).y & 0xFFFF0000u); \
        a[4] += (w_) * asf((p_).z << 16); a[5] += (w_) * asf((p_).z & 0xFFFF0000u); \
        a[6] += (w_) * asf((p_).w << 16); a[7] += (w_) * asf((p_).w & 0xFFFF0000u); \
    } while (0)

    int i = s + es;
    for (int w = 0; w < nwin; w++, i += 16) {
        float w0 = wn[i];      int c0 = col[i];
        float w1 = wn[i + 4];  int c1 = col[i + 4];
        float w2 = wn[i + 8];  int c2 = col[i + 8];
        float w3 = wn[i + 12]; int c3 = col[i + 12];
        uint4 p0 = *(const uint4*)(T1 + (size_t)c0 * HDIM + fl * 8);
        uint4 p1 = *(const uint4*)(T1 + (size_t)c1 * HDIM + fl * 8);
        uint4 p2 = *(const uint4*)(T1 + (size_t)c2 * HDIM + fl * 8);
        uint4 p3 = *(const uint4*)(T1 + (size_t)c3 * HDIM + fl * 8);
        ACCUM(w0, p0);
        ACCUM(w1, p1);
        ACCUM(w2, p2);
        ACCUM(w3, p3);
    }
    if (deg & 15) {
        int i1 = i + 4, i2 = i + 8, i3 = i + 12;
        int j0 = i  < e ? i  : (e - 1);
        int j1 = i1 < e ? i1 : (e - 1);
        int j2 = i2 < e ? i2 : (e - 1);
        int j3 = i3 < e ? i3 : (e - 1);
        float w0 = i  < e ? wn[j0] : 0.f;
        float w1 = i1 < e ? wn[j1] : 0.f;
        float w2 = i2 < e ? wn[j2] : 0.f;
        float w3 = i3 < e ? wn[j3] : 0.f;
        int c0 = col[j0], c1 = col[j1], c2 = col[j2], c3 = col[j3];
        uint4 p0 = *(const uint4*)(T1 + (size_t)c0 * HDIM + fl * 8);
        uint4 p1 = *(const uint4*)(T1 + (size_t)c1 * HDIM + fl * 8);
        uint4 p2 = *(const uint4*)(T1 + (size_t)c2 * HDIM + fl * 8);
        uint4 p3 = *(const uint4*)(T1 + (size_t)c3 * HDIM + fl * 8);
        ACCUM(w0, p0);
        ACCUM(w1, p1);
        ACCUM(w2, p2);
        ACCUM(w3, p3);
    }
#undef ACCUM

    // butterfly reduce across the 4 edge subgroups -> ALL lanes hold full sums
#pragma unroll
    for (int j = 0; j < 8; j++) {
        a[j] += __shfl_xor(a[j], 16);
        a[j] += __shfl_xor(a[j], 32);
    }

    // ---- fused epilogue: v = relu(a + b1) (f32), then U = v @ W2 ----
    const float4* bb = (const float4*)(b1 + fl * 8);
    float4 blo = bb[0], bhi = bb[1];
    float v[8];
    v[0] = a[0] + blo.x; v[1] = a[1] + blo.y;
    v[2] = a[2] + blo.z; v[3] = a[3] + blo.w;
    v[4] = a[4] + bhi.x; v[5] = a[5] + bhi.y;
    v[6] = a[6] + bhi.z; v[7] = a[7] + bhi.w;
#pragma unroll
    for (int j = 0; j < 8; j++) v[j] = v[j] > 0.f ? v[j] : 0.f;

    // this lane's 8x4 W2 tile: rows fl*8+j, cols es*4..es*4+3
    float4 p = {0.f, 0.f, 0.f, 0.f};
#pragma unroll
    for (int j = 0; j < 8; j++) {
        float4 w = *(const float4*)(W2 + (size_t)(fl * 8 + j) * CDIM + es * 4);
        p.x += v[j] * w.x;
        p.y += v[j] * w.y;
        p.z += v[j] * w.z;
        p.w += v[j] * w.w;
    }
    // reduce over fl (lane bits 0..3)
#pragma unroll
    for (int d = 1; d < 16; d <<= 1) {
        p.x += __shfl_xor(p.x, d);
        p.y += __shfl_xor(p.y, d);
        p.z += __shfl_xor(p.z, d);
        p.w += __shfl_xor(p.w, d);
    }
    if (fl == 0) {
        *(float4*)(U + (size_t)r * CDIM + es * 4) = p;
    }
}

// ---------------- K6: out = log_softmax(SpMM(U) + b2) ----------------
// 4 waves/block, 1 row/wave: 8 edge-subgroups x 8 lanes (float2/lane).
// Full windows unguarded + one guarded clamped tail window.
__global__ __launch_bounds__(256) void k_out(const float* __restrict__ U,
                                             const float* __restrict__ wn,
                                             const int* __restrict__ rowptr,
                                             const int* __restrict__ col,
                                             const float* __restrict__ b2,
                                             float* __restrict__ out, int n) {
    int wave = threadIdx.x >> 6;
    int lane = threadIdx.x & 63;
    int r = blockIdx.x * 4 + wave;
    if (r >= n) return;
    int es = lane >> 3;   // 0..7 edge slot
    int fl = lane & 7;    // feature pair: 2*fl, 2*fl+1
    int s = rowptr[r], e = rowptr[r + 1];
    int deg = e - s;
    int nwin = deg >> 4;
    float a0 = 0.f, a1 = 0.f;

    int i = s + es;
    for (int w = 0; w < nwin; w++, i += 16) {
        float w0 = wn[i];     int c0 = col[i];
        float w1 = wn[i + 8]; int c1 = col[i + 8];
        float2 u0 = *(const float2*)(U + (size_t)c0 * CDIM + fl * 2);
        float2 u1 = *(const float2*)(U + (size_t)c1 * CDIM + fl * 2);
        a0 += w0 * u0.x; a1 += w0 * u0.y;
        a0 += w1 * u1.x; a1 += w1 * u1.y;
    }
    if (deg & 15) {
        int i1 = i + 8;
        int j0 = i  < e ? i  : (e - 1);
        int j1 = i1 < e ? i1 : (e - 1);
        float w0 = i  < e ? wn[j0] : 0.f;
        float w1 = i1 < e ? wn[j1] : 0.f;
        int c0 = col[j0], c1 = col[j1];
        float2 u0 = *(const float2*)(U + (size_t)c0 * CDIM + fl * 2);
        float2 u1 = *(const float2*)(U + (size_t)c1 * CDIM + fl * 2);
        a0 += w0 * u0.x; a1 += w0 * u0.y;
        a0 += w1 * u1.x; a1 += w1 * u1.y;
    }

    a0 += __shfl_xor(a0, 8);  a1 += __shfl_xor(a1, 8);
    a0 += __shfl_xor(a0, 16); a1 += __shfl_xor(a1, 16);
    a0 += __shfl_xor(a0, 32); a1 += __shfl_xor(a1, 32);

    float2 bp = ((const float2*)b2)[fl];
    float v0 = a0 + bp.x;
    float v1 = a1 + bp.y;

    float m = fmaxf(v0, v1);
    m = fmaxf(m, __shfl_xor(m, 1));
    m = fmaxf(m, __shfl_xor(m, 2));
    m = fmaxf(m, __shfl_xor(m, 4));
    float ss = __expf(v0 - m) + __expf(v1 - m);
    ss += __shfl_xor(ss, 1);
    ss += __shfl_xor(ss, 2);
    ss += __shfl_xor(ss, 4);
    float ls = __logf(ss);
    if (es == 0) {
        float2 res = {v0 - m - ls, v1 - m - ls};
        *(float2*)(out + (size_t)r * CDIM + fl * 2) = res;
    }
}

extern "C" void kernel_launch(void* const* d_in, const int* in_sizes, int n_in,
                              void* d_out, int out_size, void* d_ws, size_t ws_size,
                              hipStream_t stream) {
    const float* x      = (const float*)d_in[0];
    const float* ew     = (const float*)d_in[1];
    const float* W1     = (const float*)d_in[2];
    const float* b1     = (const float*)d_in[3];
    const float* W2     = (const float*)d_in[4];
    const float* b2     = (const float*)d_in[5];
    const int*   rowptr = (const int*)d_in[6];
    const int*   colind = (const int*)d_in[7];

    int n = in_sizes[6] - 1;   // rowptr has n+1 entries
    int E = in_sizes[7];

    auto align256 = [](size_t v) { return (v + 255) & ~(size_t)255; };
    char* p = (char*)d_ws;
    float* dinv = (float*)p; p += align256((size_t)n * 4);
    float* wn   = (float*)p; p += align256((size_t)E * 4);
    u16*   T1   = (u16*)p;   p += align256((size_t)n * HDIM * 2);
    float* U    = (float*)p; p += align256((size_t)n * CDIM * 4);
    u16*   W1T  = (u16*)p;   p += align256((size_t)HDIM * F_IN * 2);
    float* out  = (float*)d_out;

    k_dinv<<<(n + 15) / 16, 256, 0, stream>>>(ew, rowptr, dinv, n);
    k_w<<<(n + 15) / 16, 256, 0, stream>>>(ew, rowptr, colind, dinv, wn, n);
    k_prepw1<<<(HDIM * F_IN + 255) / 256, 256, 0, stream>>>(W1, W1T);

    k_gemm1<<<(n + 255) / 256, 512, 0, stream>>>(x, W1T, T1, n);

    k_spmm1<<<(n + 3) / 4, 256, 0, stream>>>(T1, wn, rowptr, colind, b1, W2, U, n);
    k_out<<<(n + 3) / 4, 256, 0, stream>>>(U, wn, rowptr, colind, b2, out, n);
}

// Round 13
// 177.641 us; speedup vs baseline: 1.1608x; 1.1608x over previous
//
#include <hip/hip_runtime.h>
#include <hip/hip_bf16.h>

#define F_IN 256
#define HDIM 128
#define CDIM 16

typedef unsigned short u16;
typedef unsigned int u32;

typedef __attribute__((ext_vector_type(8))) short bf16x8;
typedef __attribute__((ext_vector_type(4))) float f32x4;

__device__ __forceinline__ float bf2f(u32 v) {
    u32 u = v << 16;
    float f;
    __builtin_memcpy(&f, &u, 4);
    return f;
}
__device__ __forceinline__ float asf(u32 u) {
    float f;
    __builtin_memcpy(&f, &u, 4);
    return f;
}
__device__ __forceinline__ u16 f2bf(float f) {
    u32 u;
    __builtin_memcpy(&u, &f, 4);
    u32 r = (u + 0x7FFFu + ((u >> 16) & 1u)) >> 16;
    return (u16)r;
}
// v_cvt_pk_bf16_f32: D[15:0]=bf16(lo), D[31:16]=bf16(hi), RNE
__device__ __forceinline__ u32 cvtpk(float lo, float hi) {
    u32 r;
    asm("v_cvt_pk_bf16_f32 %0, %1, %2" : "=v"(r) : "v"(lo), "v"(hi));
    return r;
}

// ---------------- K-pre: dinv[r] = rsqrt(sum ew)  +  W1T transpose ----------
// blocks [0, nbd): dinv via 16-lane subgroup per row.
// blocks [nbd, nbd+128): W1T[f][k] = bf16(W1[k][f]) (1 elem/thread).
__global__ __launch_bounds__(256) void k_pre(const float* __restrict__ ew,
                                             const int* __restrict__ rowptr,
                                             const float* __restrict__ W1,
                                             float* __restrict__ dinv,
                                             u16* __restrict__ W1T,
                                             int n, int nbd) {
    if ((int)blockIdx.x >= nbd) {
        int idx = ((int)blockIdx.x - nbd) * 256 + threadIdx.x;
        if (idx < HDIM * F_IN) {
            int f = idx >> 8;
            int k = idx & 255;
            W1T[idx] = f2bf(W1[(size_t)k * HDIM + f]);
        }
        return;
    }
    int sg = threadIdx.x >> 4;
    int sl = threadIdx.x & 15;
    int r = blockIdx.x * 16 + sg;
    if (r >= n) return;
    int s = rowptr[r], e = rowptr[r + 1];
    float acc = 0.f;
    for (int i = s + sl; i < e; i += 16) acc += ew[i];
    acc += __shfl_xor(acc, 1);
    acc += __shfl_xor(acc, 2);
    acc += __shfl_xor(acc, 4);
    acc += __shfl_xor(acc, 8);
    if (sl == 0) dinv[r] = (acc > 0.f) ? rsqrtf(acc) : 0.f;
}

// ---------------- K3: T1 = x @ W1 via bf16 MFMA, W1T in LDS ----------
// Block = 8 waves x 32 rows = 256 rows. W1T (64 KB) in LDS, XOR-swizzled.
// 2 blocks/CU -> 16 waves/CU. x global->reg, 2-stage prefetch.
// D: col = lane&15, row = (lane>>4)*4 + reg   [m89-verified]
__global__ __launch_bounds__(512, 4) void k_gemm1(const float* __restrict__ x,
                                                  const u16* __restrict__ W1T,
                                                  u16* __restrict__ T1, int n) {
    __shared__ u16 Bs[HDIM * F_IN];   // 64 KB

    int tid = threadIdx.x;
#pragma unroll
    for (int it = 0; it < 8; it++) {
        int o16 = it * 512 + tid;            // 16B-granule index 0..4095
        u32 o = (u32)o16 * 16;
        u32 swz = o ^ (((o >> 9) & 7u) << 4);
        uint4 v = ((const uint4*)W1T)[o16];
        *(uint4*)((char*)Bs + swz) = v;
    }
    __syncthreads();

    int wave = tid >> 6;
    int lane = tid & 63;
    int lr = lane & 15;
    int kg = lane >> 4;
    int r0 = blockIdx.x * 256 + wave * 32;
    if (r0 >= n) return;

    f32x4 acc[2][8];
#pragma unroll
    for (int rg = 0; rg < 2; rg++)
#pragma unroll
        for (int ct = 0; ct < 8; ct++) acc[rg][ct] = (f32x4){0.f, 0.f, 0.f, 0.f};

    const float* arow[2];
#pragma unroll
    for (int rg = 0; rg < 2; rg++) {
        int row = r0 + rg * 16 + lr;
        arow[rg] = x + (size_t)(row < n ? row : (n - 1)) * F_IN + kg * 8;
    }

    float4 laA[2], haA[2], laB[2], haB[2];

#define LOADA(L_, H_, kkv_) do { \
        _Pragma("unroll") \
        for (int rg = 0; rg < 2; rg++) { \
            const float4* ap = (const float4*)(arow[rg] + (kkv_) * 32); \
            L_[rg] = ap[0]; H_[rg] = ap[1]; \
        } } while (0)

#define COMPUTE(L_, H_, kkv_) do { \
        bf16x8 afrag[2]; \
        _Pragma("unroll") \
        for (int rg = 0; rg < 2; rg++) { \
            u32 qa[4]; \
            qa[0] = cvtpk(L_[rg].x, L_[rg].y); \
            qa[1] = cvtpk(L_[rg].z, L_[rg].w); \
            qa[2] = cvtpk(H_[rg].x, H_[rg].y); \
            qa[3] = cvtpk(H_[rg].z, H_[rg].w); \
            __builtin_memcpy(&afrag[rg], qa, 16); \
        } \
        _Pragma("unroll") \
        for (int ct = 0; ct < 8; ct++) { \
            u32 a = (u32)(ct * 16 + lr) * (F_IN * 2) + (u32)kg * 16 + (u32)(kkv_) * 64; \
            u32 aswz = a ^ (((a >> 9) & 7u) << 4); \
            bf16x8 bfrag = *(const bf16x8*)((const char*)Bs + aswz); \
            _Pragma("unroll") \
            for (int rg = 0; rg < 2; rg++) \
                acc[rg][ct] = __builtin_amdgcn_mfma_f32_16x16x32_bf16(afrag[rg], bfrag, acc[rg][ct], 0, 0, 0); \
        } } while (0)

    LOADA(laA, haA, 0);
#pragma unroll
    for (int kk = 0; kk < 8; kk += 2) {
        LOADA(laB, haB, kk + 1);
        COMPUTE(laA, haA, kk);
        if (kk + 2 < 8) LOADA(laA, haA, kk + 2);
        COMPUTE(laB, haB, kk + 1);
    }
#undef LOADA
#undef COMPUTE

    // store: T1[r0 + rg*16 + kg*4 + i][ct*16 + lr]
#pragma unroll
    for (int rg = 0; rg < 2; rg++) {
        int rbase = r0 + rg * 16 + kg * 4;
#pragma unroll
        for (int ct = 0; ct < 8; ct++) {
#pragma unroll
            for (int i = 0; i < 4; i += 2) {
                u32 q = cvtpk(acc[rg][ct][i], acc[rg][ct][i + 1]);
                int row0 = rbase + i;
                int row1 = rbase + i + 1;
                if (row0 < n) T1[(size_t)row0 * HDIM + ct * 16 + lr] = (u16)(q & 0xFFFFu);
                if (row1 < n) T1[(size_t)row1 * HDIM + ct * 16 + lr] = (u16)(q >> 16);
            }
        }
    }
}

// ---------------- K4: H = relu(SpMM(T1) + b1)  (bf16 in/out) ----------------
// 4 waves/block, 1 row/wave. Wave = 4x 16-lane subgroups, each owns one edge.
// nwin FULL windows (unguarded) + ONE guarded clamped tail window.
// Edge weight computed INLINE: w = dinv[r]*ew[i]*dinv[col[i]] (k_w deleted;
// dinv is 400 KB L2-resident so the extra broadcast gather is ~free).
__global__ __launch_bounds__(256) void k_spmm1(const u16* __restrict__ T1,
                                               const float* __restrict__ ew,
                                               const float* __restrict__ dinv,
                                               const int* __restrict__ rowptr,
                                               const int* __restrict__ col,
                                               const float* __restrict__ b1,
                                               u16* __restrict__ H, int n) {
    int wave = threadIdx.x >> 6;
    int lane = threadIdx.x & 63;
    int r = blockIdx.x * 4 + wave;
    if (r >= n) return;
    int es = lane >> 4;          // subgroup 0..3 (edge slot)
    int fl = lane & 15;          // feature group: features fl*8 .. fl*8+7

    int s = rowptr[r], e = rowptr[r + 1];
    int deg = e - s;
    int nwin = deg >> 4;
    float dr = dinv[r];
    float a[8];
#pragma unroll
    for (int j = 0; j < 8; j++) a[j] = 0.f;

#define ACCUM(w_, p_) do { \
        a[0] += (w_) * asf((p_).x << 16); a[1] += (w_) * asf((p_).x & 0xFFFF0000u); \
        a[2] += (w_) * asf((p_).y << 16); a[3] += (w_) * asf((p_).y & 0xFFFF0000u); \
        a[4] += (w_) * asf((p_).z << 16); a[5] += (w_) * asf((p_).z & 0xFFFF0000u); \
        a[6] += (w_) * asf((p_).w << 16); a[7] += (w_) * asf((p_).w & 0xFFFF0000u); \
    } while (0)

    int i = s + es;
    for (int w = 0; w < nwin; w++, i += 16) {
        float e0 = ew[i];      int c0 = col[i];
        float e1 = ew[i + 4];  int c1 = col[i + 4];
        float e2 = ew[i + 8];  int c2 = col[i + 8];
        float e3 = ew[i + 12]; int c3 = col[i + 12];
        uint4 p0 = *(const uint4*)(T1 + (size_t)c0 * HDIM + fl * 8);
        uint4 p1 = *(const uint4*)(T1 + (size_t)c1 * HDIM + fl * 8);
        uint4 p2 = *(const uint4*)(T1 + (size_t)c2 * HDIM + fl * 8);
        uint4 p3 = *(const uint4*)(T1 + (size_t)c3 * HDIM + fl * 8);
        float w0 = dr * e0 * dinv[c0];
        float w1 = dr * e1 * dinv[c1];
        float w2 = dr * e2 * dinv[c2];
        float w3 = dr * e3 * dinv[c3];
        ACCUM(w0, p0);
        ACCUM(w1, p1);
        ACCUM(w2, p2);
        ACCUM(w3, p3);
    }
    if (deg & 15) {
        int i1 = i + 4, i2 = i + 8, i3 = i + 12;
        int j0 = i  < e ? i  : (e - 1);
        int j1 = i1 < e ? i1 : (e - 1);
        int j2 = i2 < e ? i2 : (e - 1);
        int j3 = i3 < e ? i3 : (e - 1);
        int c0 = col[j0], c1 = col[j1], c2 = col[j2], c3 = col[j3];
        float w0 = i  < e ? dr * ew[j0] * dinv[c0] : 0.f;
        float w1 = i1 < e ? dr * ew[j1] * dinv[c1] : 0.f;
        float w2 = i2 < e ? dr * ew[j2] * dinv[c2] : 0.f;
        float w3 = i3 < e ? dr * ew[j3] * dinv[c3] : 0.f;
        uint4 p0 = *(const uint4*)(T1 + (size_t)c0 * HDIM + fl * 8);
        uint4 p1 = *(const uint4*)(T1 + (size_t)c1 * HDIM + fl * 8);
        uint4 p2 = *(const uint4*)(T1 + (size_t)c2 * HDIM + fl * 8);
        uint4 p3 = *(const uint4*)(T1 + (size_t)c3 * HDIM + fl * 8);
        ACCUM(w0, p0);
        ACCUM(w1, p1);
        ACCUM(w2, p2);
        ACCUM(w3, p3);
    }
#undef ACCUM

#pragma unroll
    for (int j = 0; j < 8; j++) {
        a[j] += __shfl_xor(a[j], 16);
        a[j] += __shfl_xor(a[j], 32);
    }

    if (es == 0) {
        const float4* bb = (const float4*)(b1 + fl * 8);
        float4 blo = bb[0], bhi = bb[1];
        float v0 = a[0] + blo.x, v1 = a[1] + blo.y;
        float v2 = a[2] + blo.z, v3 = a[3] + blo.w;
        float v4 = a[4] + bhi.x, v5 = a[5] + bhi.y;
        float v6 = a[6] + bhi.z, v7 = a[7] + bhi.w;
        v0 = v0 > 0.f ? v0 : 0.f; v1 = v1 > 0.f ? v1 : 0.f;
        v2 = v2 > 0.f ? v2 : 0.f; v3 = v3 > 0.f ? v3 : 0.f;
        v4 = v4 > 0.f ? v4 : 0.f; v5 = v5 > 0.f ? v5 : 0.f;
        v6 = v6 > 0.f ? v6 : 0.f; v7 = v7 > 0.f ? v7 : 0.f;
        uint4 o;
        o.x = cvtpk(v0, v1); o.y = cvtpk(v2, v3);
        o.z = cvtpk(v4, v5); o.w = cvtpk(v6, v7);
        *(uint4*)(H + (size_t)r * HDIM + fl * 8) = o;
    }
}

// ---------------- K5: U = H @ W2  (bf16 in, f32 out) ----------------
__global__ __launch_bounds__(256) void k_gemm2(const u16* __restrict__ H,
                                               const float* __restrict__ W2,
                                               float* __restrict__ U, int n) {
    int rl = threadIdx.x >> 4;
    int f = threadIdx.x & 15;
    int row = blockIdx.x * 16 + rl;
    if (row >= n) return;
    const u32* hr = (const u32*)(H + (size_t)row * HDIM);
    float acc = 0.f;
    for (int k2 = 0; k2 < HDIM / 2; k2++) {
        u32 pr = hr[k2];
        float h0 = asf(pr << 16);
        float h1 = asf(pr & 0xFFFF0000u);
        acc += h0 * W2[(size_t)(k2 * 2) * CDIM + f];
        acc += h1 * W2[(size_t)(k2 * 2 + 1) * CDIM + f];
    }
    U[(size_t)row * CDIM + f] = acc;
}

// ---------------- K6: out = log_softmax(SpMM(U) + b2) ----------------
// 4 waves/block, 1 row/wave: 8 edge-subgroups x 8 lanes (float2/lane).
// Full windows unguarded + one guarded clamped tail window. Inline w.
__global__ __launch_bounds__(256) void k_out(const float* __restrict__ U,
                                             const float* __restrict__ ew,
                                             const float* __restrict__ dinv,
                                             const int* __restrict__ rowptr,
                                             const int* __restrict__ col,
                                             const float* __restrict__ b2,
                                             float* __restrict__ out, int n) {
    int wave = threadIdx.x >> 6;
    int lane = threadIdx.x & 63;
    int r = blockIdx.x * 4 + wave;
    if (r >= n) return;
    int es = lane >> 3;   // 0..7 edge slot
    int fl = lane & 7;    // feature pair: 2*fl, 2*fl+1
    int s = rowptr[r], e = rowptr[r + 1];
    int deg = e - s;
    int nwin = deg >> 4;
    float dr = dinv[r];
    float a0 = 0.f, a1 = 0.f;

    int i = s + es;
    for (int w = 0; w < nwin; w++, i += 16) {
        float e0 = ew[i];     int c0 = col[i];
        float e1 = ew[i + 8]; int c1 = col[i + 8];
        float2 u0 = *(const float2*)(U + (size_t)c0 * CDIM + fl * 2);
        float2 u1 = *(const float2*)(U + (size_t)c1 * CDIM + fl * 2);
        float w0 = dr * e0 * dinv[c0];
        float w1 = dr * e1 * dinv[c1];
        a0 += w0 * u0.x; a1 += w0 * u0.y;
        a0 += w1 * u1.x; a1 += w1 * u1.y;
    }
    if (deg & 15) {
        int i1 = i + 8;
        int j0 = i  < e ? i  : (e - 1);
        int j1 = i1 < e ? i1 : (e - 1);
        int c0 = col[j0], c1 = col[j1];
        float w0 = i  < e ? dr * ew[j0] * dinv[c0] : 0.f;
        float w1 = i1 < e ? dr * ew[j1] * dinv[c1] : 0.f;
        float2 u0 = *(const float2*)(U + (size_t)c0 * CDIM + fl * 2);
        float2 u1 = *(const float2*)(U + (size_t)c1 * CDIM + fl * 2);
        a0 += w0 * u0.x; a1 += w0 * u0.y;
        a0 += w1 * u1.x; a1 += w1 * u1.y;
    }

    a0 += __shfl_xor(a0, 8);  a1 += __shfl_xor(a1, 8);
    a0 += __shfl_xor(a0, 16); a1 += __shfl_xor(a1, 16);
    a0 += __shfl_xor(a0, 32); a1 += __shfl_xor(a1, 32);

    float2 bp = ((const float2*)b2)[fl];
    float v0 = a0 + bp.x;
    float v1 = a1 + bp.y;

    float m = fmaxf(v0, v1);
    m = fmaxf(m, __shfl_xor(m, 1));
    m = fmaxf(m, __shfl_xor(m, 2));
    m = fmaxf(m, __shfl_xor(m, 4));
    float ss = __expf(v0 - m) + __expf(v1 - m);
    ss += __shfl_xor(ss, 1);
    ss += __shfl_xor(ss, 2);
    ss += __shfl_xor(ss, 4);
    float ls = __logf(ss);
    if (es == 0) {
        float2 res = {v0 - m - ls, v1 - m - ls};
        *(float2*)(out + (size_t)r * CDIM + fl * 2) = res;
    }
}

extern "C" void kernel_launch(void* const* d_in, const int* in_sizes, int n_in,
                              void* d_out, int out_size, void* d_ws, size_t ws_size,
                              hipStream_t stream) {
    const float* x      = (const float*)d_in[0];
    const float* ew     = (const float*)d_in[1];
    const float* W1     = (const float*)d_in[2];
    const float* b1     = (const float*)d_in[3];
    const float* W2     = (const float*)d_in[4];
    const float* b2     = (const float*)d_in[5];
    const int*   rowptr = (const int*)d_in[6];
    const int*   colind = (const int*)d_in[7];

    int n = in_sizes[6] - 1;   // rowptr has n+1 entries
    int E = in_sizes[7];
    (void)E;

    auto align256 = [](size_t v) { return (v + 255) & ~(size_t)255; };
    char* p = (char*)d_ws;
    float* dinv = (float*)p; p += align256((size_t)n * 4);
    u16*   T1   = (u16*)p;   p += align256((size_t)n * HDIM * 2);
    u16*   H    = (u16*)p;   p += align256((size_t)n * HDIM * 2);
    float* U    = (float*)p; p += align256((size_t)n * CDIM * 4);
    u16*   W1T  = (u16*)p;   p += align256((size_t)HDIM * F_IN * 2);
    float* out  = (float*)d_out;

    int nbd = (n + 15) / 16;
    k_pre<<<nbd + 128, 256, 0, stream>>>(ew, rowptr, W1, dinv, W1T, n, nbd);

    k_gemm1<<<(n + 255) / 256, 512, 0, stream>>>(x, W1T, T1, n);

    k_spmm1<<<(n + 3) / 4, 256, 0, stream>>>(T1, ew, dinv, rowptr, colind, b1, H, n);
    k_gemm2<<<(n + 15) / 16, 256, 0, stream>>>(H, W2, U, n);
    k_out<<<(n + 3) / 4, 256, 0, stream>>>(U, ew, dinv, rowptr, colind, b2, out, n);
}